// Round 1
// baseline (138.103 us; speedup 1.0000x reference)
//
#include <hip/hip_runtime.h>
#include <math.h>

#define DIM 4096
#define NH 32
#define NKV 8
#define HD 128
#define B_ 8
#define SW 4096
#define PAD_LEN 2048
#define GQ 4            // NH / NKV
#define KSPLIT 16
#define KCHUNK 256      // DIM / KSPLIT
#define QKV_COLS (DIM + 2 * NKV * HD)   // 6144
#define LCHUNK 256
#define NLCHUNK (PAD_LEN / LCHUNK)      // 8
#define SCALE 0.08838834764831845f      // 1/sqrt(128)

// ---------------- workspace layout (float offsets) ----------------
#define OFF_QKVP   0                                   // KSPLIT*B_*QKV_COLS = 786432
#define OFF_Q      (OFF_QKVP + KSPLIT * B_ * QKV_COLS) // +32768
#define OFF_K      (OFF_Q + B_ * DIM)                  // +8192
#define OFF_V      (OFF_K + B_ * NKV * HD)             // +8192
#define OFF_AP     (OFF_V + B_ * NKV * HD)             // +64*8*4*130 = 266240
#define OFF_AO     (OFF_AP + B_ * NKV * NLCHUNK * GQ * (HD + 2)) // +32768
#define OFF_OP     (OFF_AO + B_ * DIM)                 // +KSPLIT*B_*DIM = 524288

// ---------------- kernel 1: q/k/v projection, split-K partials ----------------
__global__ void qkv_partial(const float* __restrict__ x,
                            const float* __restrict__ wq,
                            const float* __restrict__ wk,
                            const float* __restrict__ wv,
                            float* __restrict__ part) {
    __shared__ float xs[B_][KCHUNK];
    const int tid = threadIdx.x;
    const int col = blockIdx.x * 256 + tid;
    const int k0  = blockIdx.y * KCHUNK;

    #pragma unroll
    for (int i = 0; i < (B_ * KCHUNK) / 256; ++i) {
        int idx = i * 256 + tid;
        int r   = idx >> 8;           // / KCHUNK
        int kk  = idx & (KCHUNK - 1);
        xs[r][kk] = x[r * DIM + k0 + kk];
    }
    __syncthreads();

    const float* W;
    int ldw, c;
    if (col < DIM)                { W = wq; ldw = NH * HD;  c = col; }
    else if (col < DIM + NKV*HD)  { W = wk; ldw = NKV * HD; c = col - DIM; }
    else                          { W = wv; ldw = NKV * HD; c = col - DIM - NKV * HD; }

    float acc[B_] = {0.f, 0.f, 0.f, 0.f, 0.f, 0.f, 0.f, 0.f};
    const float* wp = W + (size_t)k0 * ldw + c;
    #pragma unroll 4
    for (int kk = 0; kk < KCHUNK; ++kk) {
        float w = wp[(size_t)kk * ldw];
        #pragma unroll
        for (int r = 0; r < B_; ++r) acc[r] = fmaf(xs[r][kk], w, acc[r]);
    }
    #pragma unroll
    for (int r = 0; r < B_; ++r)
        part[((size_t)(blockIdx.y * B_ + r)) * QKV_COLS + col] = acc[r];
}

// ---------------- kernel 2: reduce partials + RoPE ----------------
__global__ void qkv_reduce_rope(const float* __restrict__ part,
                                const float* __restrict__ rot,   // (B, HD, HD)
                                float* __restrict__ qb,
                                float* __restrict__ kb,
                                float* __restrict__ vb) {
    const int tid = threadIdx.x;
    const int col = blockIdx.x * 256 + tid;
    const int r   = blockIdx.y;   // batch row

    float v = 0.f;
    #pragma unroll
    for (int s = 0; s < KSPLIT; ++s)
        v += part[((size_t)(s * B_ + r)) * QKV_COLS + col];

    if (col < DIM + NKV * HD) {
        // RoPE: pair (2i, 2i+1) within the head
        int hd = col & (HD - 1);
        int i2 = hd & ~1;
        const float* rm = rot + (size_t)r * HD * HD;
        float c = rm[i2 * HD + i2];          // cos
        float s = rm[(i2 + 1) * HD + i2];    // sin
        float partner = __shfl_xor(v, 1, 64);
        float outv = (hd & 1) ? (v * c - partner * s) : (v * c + partner * s);
        if (col < DIM) qb[r * DIM + col] = outv;
        else           kb[r * NKV * HD + (col - DIM)] = outv;
    } else {
        vb[r * NKV * HD + (col - DIM - NKV * HD)] = v;
    }
}

// ---------------- kernel 3: attention, split-L partials ----------------
__global__ void attn_partial(const float* __restrict__ qb,
                             const float* __restrict__ knew,
                             const float* __restrict__ vnew,
                             const float* __restrict__ cache_k,
                             const float* __restrict__ cache_v,
                             const float* __restrict__ mask,     // (NH, B, PAD_LEN)
                             const int* __restrict__ start_pos_p,
                             float* __restrict__ part) {
    const int bg = blockIdx.x;          // 0..63
    const int b  = bg >> 3;
    const int g  = bg & 7;
    const int chunk = blockIdx.y;       // 0..NLCHUNK-1
    const int l0 = chunk * LCHUNK;
    const int tid = threadIdx.x;
    const int sp = start_pos_p[0];

    __shared__ float q_lds[GQ][HD];
    __shared__ float p_lds[GQ][LCHUNK];
    __shared__ float red[256];

    for (int i = tid; i < GQ * HD; i += 256) {
        int qh = i >> 7;
        int d  = i & (HD - 1);
        q_lds[qh][d] = qb[b * DIM + (g * GQ + qh) * HD + d];
    }
    __syncthreads();

    const int l = l0 + tid;
    const float* krow = (l == sp) ? (knew + (b * NKV + g) * HD)
                                  : (cache_k + (((size_t)(b * NKV + g)) * SW + l) * HD);
    float s[GQ] = {0.f, 0.f, 0.f, 0.f};
    const float4* k4 = (const float4*)krow;
    #pragma unroll 8
    for (int j = 0; j < HD / 4; ++j) {
        float4 kv = k4[j];
        #pragma unroll
        for (int qh = 0; qh < GQ; ++qh) {
            s[qh] += kv.x * q_lds[qh][4*j]   + kv.y * q_lds[qh][4*j+1]
                   + kv.z * q_lds[qh][4*j+2] + kv.w * q_lds[qh][4*j+3];
        }
    }

    float m[GQ], sum[GQ];
    for (int qh = 0; qh < GQ; ++qh) {
        float sv = s[qh] * SCALE
                 + mask[(((size_t)(g * GQ + qh)) * B_ + b) * PAD_LEN + l];
        red[tid] = sv; __syncthreads();
        for (int st = 128; st > 0; st >>= 1) {
            if (tid < st) red[tid] = fmaxf(red[tid], red[tid + st]);
            __syncthreads();
        }
        m[qh] = red[0]; __syncthreads();
        float p = __expf(sv - m[qh]);
        p_lds[qh][tid] = p;
        red[tid] = p; __syncthreads();
        for (int st = 128; st > 0; st >>= 1) {
            if (tid < st) red[tid] += red[tid + st];
            __syncthreads();
        }
        sum[qh] = red[0]; __syncthreads();
    }

    // PV: thread owns (h2, d) and (h2+2, d)
    const int d  = tid & (HD - 1);
    const int h2 = tid >> 7;            // 0 or 1
    float acc0 = 0.f, acc1 = 0.f;
    for (int ll = 0; ll < LCHUNK; ++ll) {
        int lg = l0 + ll;
        float vv = (lg == sp) ? vnew[(b * NKV + g) * HD + d]
                              : cache_v[(((size_t)(b * NKV + g)) * SW + lg) * HD + d];
        acc0 = fmaf(p_lds[h2][ll],     vv, acc0);
        acc1 = fmaf(p_lds[h2 + 2][ll], vv, acc1);
    }

    const size_t base = ((size_t)bg * NLCHUNK + chunk) * GQ;
    part[(base + h2)     * (HD + 2) + 2 + d] = acc0;
    part[(base + h2 + 2) * (HD + 2) + 2 + d] = acc1;
    if (tid < GQ) {
        part[(base + tid) * (HD + 2) + 0] = m[tid];
        part[(base + tid) * (HD + 2) + 1] = sum[tid];
    }
}

// ---------------- kernel 4: combine split-L partials ----------------
__global__ void attn_combine(const float* __restrict__ part,
                             float* __restrict__ attnout) {
    const int bg = blockIdx.x;
    const int b  = bg >> 3;
    const int g  = bg & 7;
    const int d  = threadIdx.x;   // 128

    for (int qh = 0; qh < GQ; ++qh) {
        float M = -3.4e38f;
        #pragma unroll
        for (int c = 0; c < NLCHUNK; ++c)
            M = fmaxf(M, part[(((size_t)bg * NLCHUNK + c) * GQ + qh) * (HD + 2)]);
        float denom = 0.f, o = 0.f;
        #pragma unroll
        for (int c = 0; c < NLCHUNK; ++c) {
            const float* p = part + (((size_t)bg * NLCHUNK + c) * GQ + qh) * (HD + 2);
            float w = __expf(p[0] - M);
            denom += w * p[1];
            o     += w * p[2 + d];
        }
        attnout[b * DIM + (g * GQ + qh) * HD + d] = o / denom;
    }
}

// ---------------- kernel 5: output projection, split-K partials ----------------
__global__ void oproj_partial(const float* __restrict__ xin,
                              const float* __restrict__ wo,
                              float* __restrict__ part) {
    __shared__ float xs[B_][KCHUNK];
    const int tid = threadIdx.x;
    const int col = blockIdx.x * 256 + tid;
    const int k0  = blockIdx.y * KCHUNK;

    #pragma unroll
    for (int i = 0; i < (B_ * KCHUNK) / 256; ++i) {
        int idx = i * 256 + tid;
        int r   = idx >> 8;
        int kk  = idx & (KCHUNK - 1);
        xs[r][kk] = xin[r * DIM + k0 + kk];
    }
    __syncthreads();

    float acc[B_] = {0.f, 0.f, 0.f, 0.f, 0.f, 0.f, 0.f, 0.f};
    const float* wp = wo + (size_t)k0 * DIM + col;
    #pragma unroll 4
    for (int kk = 0; kk < KCHUNK; ++kk) {
        float w = wp[(size_t)kk * DIM];
        #pragma unroll
        for (int r = 0; r < B_; ++r) acc[r] = fmaf(xs[r][kk], w, acc[r]);
    }
    #pragma unroll
    for (int r = 0; r < B_; ++r)
        part[((size_t)(blockIdx.y * B_ + r)) * DIM + col] = acc[r];
}

// ---------------- kernel 6: reduce -> final output ----------------
__global__ void oproj_reduce(const float* __restrict__ part,
                             float* __restrict__ out) {
    const int tid = threadIdx.x;
    const int col = blockIdx.x * 256 + tid;
    const int r   = blockIdx.y;
    float v = 0.f;
    #pragma unroll
    for (int s = 0; s < KSPLIT; ++s)
        v += part[((size_t)(s * B_ + r)) * DIM + col];
    out[r * DIM + col] = v;
}

extern "C" void kernel_launch(void* const* d_in, const int* in_sizes, int n_in,
                              void* d_out, int out_size, void* d_ws, size_t ws_size,
                              hipStream_t stream) {
    const float* x        = (const float*)d_in[0];
    const float* wq       = (const float*)d_in[1];
    const float* wk       = (const float*)d_in[2];
    const float* wv       = (const float*)d_in[3];
    const float* wo       = (const float*)d_in[4];
    const float* rot      = (const float*)d_in[5];
    const float* cache_k  = (const float*)d_in[6];
    const float* cache_v  = (const float*)d_in[7];
    const float* mask     = (const float*)d_in[8];
    const int*   start_pp = (const int*)d_in[9];
    float* ws  = (float*)d_ws;
    float* out = (float*)d_out;

    dim3 gA(QKV_COLS / 256, KSPLIT);
    qkv_partial<<<gA, 256, 0, stream>>>(x, wq, wk, wv, ws + OFF_QKVP);

    dim3 gB(QKV_COLS / 256, B_);
    qkv_reduce_rope<<<gB, 256, 0, stream>>>(ws + OFF_QKVP, rot,
                                            ws + OFF_Q, ws + OFF_K, ws + OFF_V);

    dim3 gC(B_ * NKV, NLCHUNK);
    attn_partial<<<gC, 256, 0, stream>>>(ws + OFF_Q, ws + OFF_K, ws + OFF_V,
                                         cache_k, cache_v, mask, start_pp,
                                         ws + OFF_AP);

    attn_combine<<<dim3(B_ * NKV), 128, 0, stream>>>(ws + OFF_AP, ws + OFF_AO);

    dim3 gD(DIM / 256, KSPLIT);
    oproj_partial<<<gD, 256, 0, stream>>>(ws + OFF_AO, wo, ws + OFF_OP);

    dim3 gE(DIM / 256, B_);
    oproj_reduce<<<gE, 256, 0, stream>>>(ws + OFF_OP, out);
}

// Round 2
// 129.337 us; speedup vs baseline: 1.0678x; 1.0678x over previous
//
#include <hip/hip_runtime.h>
#include <math.h>

#define DIM 4096
#define NH 32
#define NKV 8
#define HD 128
#define B_ 8
#define SW 4096
#define PAD_LEN 2048
#define GQ 4                    // NH / NKV
#define QKV_COLS (DIM + 2 * NKV * HD)   // 6144
#define KSQ 64                  // qkv split-K
#define KCQ (DIM / KSQ)         // 64
#define KSO 64                  // oproj split-K
#define KCO (DIM / KSO)         // 64
#define LCHUNK 256
#define NLCHUNK (PAD_LEN / LCHUNK)      // 8
#define SCALE 0.08838834764831845f      // 1/sqrt(128)

// ---------------- workspace layout (float offsets) ----------------
#define OFF_QKVP   0                                      // KSQ*B_*QKV_COLS = 3145728
#define OFF_Q      (OFF_QKVP + KSQ * B_ * QKV_COLS)
#define OFF_K      (OFF_Q + B_ * DIM)
#define OFF_V      (OFF_K + B_ * NKV * HD)
#define OFF_AP     (OFF_V + B_ * NKV * HD)
#define OFF_AO     (OFF_AP + B_ * NKV * NLCHUNK * GQ * (HD + 2))
#define OFF_OP     (OFF_AO + B_ * DIM)                    // KSO*B_*DIM

// ---------------- kernel 1: q/k/v projection, split-K, float2 cols ----------------
__global__ void qkv_partial(const float* __restrict__ x,
                            const float* __restrict__ wq,
                            const float* __restrict__ wk,
                            const float* __restrict__ wv,
                            float* __restrict__ part) {
    __shared__ float xs[B_][KCQ];
    const int tid = threadIdx.x;
    const int k0  = blockIdx.y * KCQ;

    {   // stage x chunk: 512 floats via float2
        int idx = tid * 2;
        int r   = idx >> 6;
        int kk  = idx & (KCQ - 1);
        float2 xv = *(const float2*)(x + r * DIM + k0 + kk);
        xs[r][kk]     = xv.x;
        xs[r][kk + 1] = xv.y;
    }
    __syncthreads();

    // block covers 512 columns; uniform weight matrix per block
    const int bx = blockIdx.x;
    const float* W;
    int ldw, cbase;
    if (bx < 8)       { W = wq; ldw = NH * HD;  cbase = bx * 512; }
    else if (bx < 10) { W = wk; ldw = NKV * HD; cbase = (bx - 8) * 512; }
    else              { W = wv; ldw = NKV * HD; cbase = (bx - 10) * 512; }
    const int c = cbase + tid * 2;

    float2 acc[B_];
    #pragma unroll
    for (int r = 0; r < B_; ++r) { acc[r].x = 0.f; acc[r].y = 0.f; }

    const float* wp = W + (size_t)k0 * ldw + c;
    #pragma unroll 8
    for (int kk = 0; kk < KCQ; ++kk) {
        float2 w = *(const float2*)(wp + (size_t)kk * ldw);
        #pragma unroll
        for (int r = 0; r < B_; ++r) {
            float xv = xs[r][kk];
            acc[r].x = fmaf(xv, w.x, acc[r].x);
            acc[r].y = fmaf(xv, w.y, acc[r].y);
        }
    }
    const int colg = bx * 512 + tid * 2;
    #pragma unroll
    for (int r = 0; r < B_; ++r)
        *(float2*)(part + ((size_t)(blockIdx.y * B_ + r)) * QKV_COLS + colg) = acc[r];
}

// ---------------- kernel 2: reduce partials + RoPE (float2 = rope pair) ----------------
__global__ void qkv_reduce_rope(const float* __restrict__ part,
                                const float* __restrict__ rot,   // (B, HD, HD)
                                float* __restrict__ qb,
                                float* __restrict__ kb,
                                float* __restrict__ vb) {
    const int tid  = threadIdx.x;
    const int col2 = blockIdx.x * 256 + tid;   // float2 index, [0, 3072)
    const int col  = col2 * 2;
    const int r    = blockIdx.y;

    float2 v; v.x = 0.f; v.y = 0.f;
    #pragma unroll 8
    for (int s = 0; s < KSQ; ++s) {
        float2 p = *(const float2*)(part + ((size_t)(s * B_ + r)) * QKV_COLS + col);
        v.x += p.x; v.y += p.y;
    }

    if (col < DIM + NKV * HD) {
        int hd = col & (HD - 1);                 // even
        const float* rm = rot + (size_t)r * HD * HD;
        float c  = rm[hd * HD + hd];             // cos
        float sn = rm[(hd + 1) * HD + hd];       // sin
        float2 o;
        o.x = v.x * c + v.y * sn;                // even element
        o.y = v.y * c - v.x * sn;                // odd element
        if (col < DIM) *(float2*)(qb + r * DIM + col) = o;
        else           *(float2*)(kb + r * NKV * HD + (col - DIM)) = o;
    } else {
        *(float2*)(vb + r * NKV * HD + (col - DIM - NKV * HD)) = v;
    }
}

// ---------------- kernel 3: attention, split-L, shuffle softmax ----------------
__global__ void attn_partial(const float* __restrict__ qb,
                             const float* __restrict__ knew,
                             const float* __restrict__ vnew,
                             const float* __restrict__ cache_k,
                             const float* __restrict__ cache_v,
                             const float* __restrict__ mask,     // (NH, B, PAD_LEN)
                             const int* __restrict__ start_pos_p,
                             float* __restrict__ part) {
    const int bg = blockIdx.x;          // 0..63
    const int b  = bg >> 3;
    const int g  = bg & 7;
    const int chunk = blockIdx.y;       // 0..NLCHUNK-1
    const int l0 = chunk * LCHUNK;
    const int tid = threadIdx.x;
    const int sp = start_pos_p[0];

    __shared__ float q_lds[GQ][HD];
    __shared__ float p_lds[GQ][LCHUNK];
    __shared__ float crossm[4][GQ];
    __shared__ float crosss[4][GQ];

    for (int i = tid; i < GQ * HD; i += 256) {
        int qh = i >> 7;
        int d  = i & (HD - 1);
        q_lds[qh][d] = qb[b * DIM + (g * GQ + qh) * HD + d];
    }
    __syncthreads();

    // ---- QK^T: thread owns key row l ----
    const int l = l0 + tid;
    const float* krow = (l == sp) ? (knew + (b * NKV + g) * HD)
                                  : (cache_k + (((size_t)(b * NKV + g)) * SW + l) * HD);
    float s[GQ] = {0.f, 0.f, 0.f, 0.f};
    const float4* k4 = (const float4*)krow;
    #pragma unroll 8
    for (int j = 0; j < HD / 4; ++j) {
        float4 kv = k4[j];
        #pragma unroll
        for (int qh = 0; qh < GQ; ++qh) {
            s[qh] += kv.x * q_lds[qh][4*j]   + kv.y * q_lds[qh][4*j+1]
                   + kv.z * q_lds[qh][4*j+2] + kv.w * q_lds[qh][4*j+3];
        }
    }
    float sv[GQ];
    #pragma unroll
    for (int qh = 0; qh < GQ; ++qh)
        sv[qh] = s[qh] * SCALE
               + mask[(((size_t)(g * GQ + qh)) * B_ + b) * PAD_LEN + l];

    // ---- block max via wave shuffles + tiny LDS cross ----
    const int wave = tid >> 6;
    const int lane = tid & 63;
    float wm[GQ];
    #pragma unroll
    for (int qh = 0; qh < GQ; ++qh) wm[qh] = sv[qh];
    #pragma unroll
    for (int off = 32; off > 0; off >>= 1)
        #pragma unroll
        for (int qh = 0; qh < GQ; ++qh)
            wm[qh] = fmaxf(wm[qh], __shfl_xor(wm[qh], off, 64));
    if (lane == 0)
        #pragma unroll
        for (int qh = 0; qh < GQ; ++qh) crossm[wave][qh] = wm[qh];
    __syncthreads();
    float m[GQ];
    #pragma unroll
    for (int qh = 0; qh < GQ; ++qh)
        m[qh] = fmaxf(fmaxf(crossm[0][qh], crossm[1][qh]),
                      fmaxf(crossm[2][qh], crossm[3][qh]));

    // ---- exp + block sum ----
    float wsum[GQ];
    #pragma unroll
    for (int qh = 0; qh < GQ; ++qh) {
        float p = __expf(sv[qh] - m[qh]);
        p_lds[qh][tid] = p;
        wsum[qh] = p;
    }
    #pragma unroll
    for (int off = 32; off > 0; off >>= 1)
        #pragma unroll
        for (int qh = 0; qh < GQ; ++qh)
            wsum[qh] += __shfl_xor(wsum[qh], off, 64);
    if (lane == 0)
        #pragma unroll
        for (int qh = 0; qh < GQ; ++qh) crosss[wave][qh] = wsum[qh];
    __syncthreads();   // also guarantees p_lds complete
    float sum[GQ];
    #pragma unroll
    for (int qh = 0; qh < GQ; ++qh)
        sum[qh] = crosss[0][qh] + crosss[1][qh] + crosss[2][qh] + crosss[3][qh];

    // ---- PV: wave = query head, float2 over d ----
    const int qh = wave;
    const int d2 = lane * 2;
    float2 acc; acc.x = 0.f; acc.y = 0.f;
    const float* vbase = cache_v + (((size_t)(b * NKV + g)) * SW) * HD + d2;
    const float* vnewp = vnew + (b * NKV + g) * HD + d2;
    #pragma unroll 4
    for (int ll = 0; ll < LCHUNK; ++ll) {
        int lg = l0 + ll;
        const float* vp = (lg == sp) ? vnewp : (vbase + (size_t)lg * HD);
        float2 vv = *(const float2*)vp;
        float p = p_lds[qh][ll];
        acc.x = fmaf(p, vv.x, acc.x);
        acc.y = fmaf(p, vv.y, acc.y);
    }

    const size_t base = ((size_t)bg * NLCHUNK + chunk) * GQ;
    *(float2*)(part + (base + qh) * (HD + 2) + 2 + d2) = acc;
    if (tid < GQ) {
        part[(base + tid) * (HD + 2) + 0] = m[tid];
        part[(base + tid) * (HD + 2) + 1] = sum[tid];
    }
}

// ---------------- kernel 4: combine split-L partials ----------------
__global__ void attn_combine(const float* __restrict__ part,
                             float* __restrict__ attnout) {
    const int bg = blockIdx.x;
    const int b  = bg >> 3;
    const int g  = bg & 7;
    const int d  = threadIdx.x;   // 128

    for (int qh = 0; qh < GQ; ++qh) {
        float M = -3.4e38f;
        #pragma unroll
        for (int c = 0; c < NLCHUNK; ++c)
            M = fmaxf(M, part[(((size_t)bg * NLCHUNK + c) * GQ + qh) * (HD + 2)]);
        float denom = 0.f, o = 0.f;
        #pragma unroll
        for (int c = 0; c < NLCHUNK; ++c) {
            const float* p = part + (((size_t)bg * NLCHUNK + c) * GQ + qh) * (HD + 2);
            float w = __expf(p[0] - M);
            denom += w * p[1];
            o     += w * p[2 + d];
        }
        attnout[b * DIM + (g * GQ + qh) * HD + d] = o / denom;
    }
}

// ---------------- kernel 5: output projection, split-K, float2 cols ----------------
__global__ void oproj_partial(const float* __restrict__ xin,
                              const float* __restrict__ wo,
                              float* __restrict__ part) {
    __shared__ float xs[B_][KCO];
    const int tid = threadIdx.x;
    const int k0  = blockIdx.y * KCO;

    {
        int idx = tid * 2;
        int r   = idx >> 6;
        int kk  = idx & (KCO - 1);
        float2 xv = *(const float2*)(xin + r * DIM + k0 + kk);
        xs[r][kk]     = xv.x;
        xs[r][kk + 1] = xv.y;
    }
    __syncthreads();

    const int col = blockIdx.x * 512 + tid * 2;
    float2 acc[B_];
    #pragma unroll
    for (int r = 0; r < B_; ++r) { acc[r].x = 0.f; acc[r].y = 0.f; }

    const float* wp = wo + (size_t)k0 * DIM + col;
    #pragma unroll 8
    for (int kk = 0; kk < KCO; ++kk) {
        float2 w = *(const float2*)(wp + (size_t)kk * DIM);
        #pragma unroll
        for (int r = 0; r < B_; ++r) {
            float xv = xs[r][kk];
            acc[r].x = fmaf(xv, w.x, acc[r].x);
            acc[r].y = fmaf(xv, w.y, acc[r].y);
        }
    }
    #pragma unroll
    for (int r = 0; r < B_; ++r)
        *(float2*)(part + ((size_t)(blockIdx.y * B_ + r)) * DIM + col) = acc[r];
}

// ---------------- kernel 6: reduce -> final output ----------------
__global__ void oproj_reduce(const float* __restrict__ part,
                             float* __restrict__ out) {
    const int tid = threadIdx.x;
    const int col = (blockIdx.x * 256 + tid) * 2;
    const int r   = blockIdx.y;
    float2 v; v.x = 0.f; v.y = 0.f;
    #pragma unroll 8
    for (int s = 0; s < KSO; ++s) {
        float2 p = *(const float2*)(part + ((size_t)(s * B_ + r)) * DIM + col);
        v.x += p.x; v.y += p.y;
    }
    *(float2*)(out + r * DIM + col) = v;
}

extern "C" void kernel_launch(void* const* d_in, const int* in_sizes, int n_in,
                              void* d_out, int out_size, void* d_ws, size_t ws_size,
                              hipStream_t stream) {
    const float* x        = (const float*)d_in[0];
    const float* wq       = (const float*)d_in[1];
    const float* wk       = (const float*)d_in[2];
    const float* wv       = (const float*)d_in[3];
    const float* wo       = (const float*)d_in[4];
    const float* rot      = (const float*)d_in[5];
    const float* cache_k  = (const float*)d_in[6];
    const float* cache_v  = (const float*)d_in[7];
    const float* mask     = (const float*)d_in[8];
    const int*   start_pp = (const int*)d_in[9];
    float* ws  = (float*)d_ws;
    float* out = (float*)d_out;

    dim3 gA(QKV_COLS / 512, KSQ);          // (12, 64)
    qkv_partial<<<gA, 256, 0, stream>>>(x, wq, wk, wv, ws + OFF_QKVP);

    dim3 gB((QKV_COLS / 2) / 256, B_);     // (12, 8)
    qkv_reduce_rope<<<gB, 256, 0, stream>>>(ws + OFF_QKVP, rot,
                                            ws + OFF_Q, ws + OFF_K, ws + OFF_V);

    dim3 gC(B_ * NKV, NLCHUNK);            // (64, 8)
    attn_partial<<<gC, 256, 0, stream>>>(ws + OFF_Q, ws + OFF_K, ws + OFF_V,
                                         cache_k, cache_v, mask, start_pp,
                                         ws + OFF_AP);

    attn_combine<<<dim3(B_ * NKV), 128, 0, stream>>>(ws + OFF_AP, ws + OFF_AO);

    dim3 gD(DIM / 512, KSO);               // (8, 64)
    oproj_partial<<<gD, 256, 0, stream>>>(ws + OFF_AO, wo, ws + OFF_OP);

    dim3 gE((DIM / 2) / 256, B_);          // (8, 8)
    oproj_reduce<<<gE, 256, 0, stream>>>(ws + OFF_OP, out);
}

// Round 3
// 115.950 us; speedup vs baseline: 1.1911x; 1.1155x over previous
//
#include <hip/hip_runtime.h>
#include <math.h>

#define DIM 4096
#define NH 32
#define NKV 8
#define HD 128
#define B_ 8
#define SW 4096
#define PAD_LEN 2048
#define GQ 4                        // NH / NKV
#define QKV_COLS (DIM + 2 * NKV * HD)   // 6144
#define KSQ 128                     // qkv split-K
#define KCQ (DIM / KSQ)             // 32
#define KSO 128                     // oproj split-K
#define KCO (DIM / KSO)             // 32
#define LCHUNK 64
#define NLCHUNK (PAD_LEN / LCHUNK)  // 32
#define SCALE 0.08838834764831845f  // 1/sqrt(128)

// ---------------- workspace layout (float offsets) ----------------
#define OFF_QKVP   0                                        // KSQ*B_*QKV_COLS
#define OFF_Q      (OFF_QKVP + KSQ * B_ * QKV_COLS)
#define OFF_K      (OFF_Q + B_ * DIM)
#define OFF_V      (OFF_K + B_ * NKV * HD)
#define OFF_AP     (OFF_V + B_ * NKV * HD)
#define OFF_AO     (OFF_AP + B_ * NKV * NLCHUNK * GQ * (HD + 2))
#define OFF_OP     (OFF_AO + B_ * DIM)                      // KSO*B_*DIM

// ---------------- kernel 1: q/k/v projection, split-K, float4 cols ----------------
__global__ __launch_bounds__(256)
void qkv_partial(const float* __restrict__ x,
                 const float* __restrict__ wq,
                 const float* __restrict__ wk,
                 const float* __restrict__ wv,
                 float* __restrict__ part) {
    __shared__ float xs[B_][KCQ];           // 8 x 32
    const int tid = threadIdx.x;
    const int k0  = blockIdx.y * KCQ;

    if (tid < 64) {                          // 8 rows x 8 float4
        int r  = tid >> 3;
        int kk = (tid & 7) * 4;
        *(float4*)&xs[r][kk] = *(const float4*)(x + r * DIM + k0 + kk);
    }
    __syncthreads();

    const int bx = blockIdx.x;               // 0..5: 4 wq blocks, 1 wk, 1 wv
    const float* W;
    int ldw, cbase;
    if (bx < 4)       { W = wq; ldw = NH * HD;  cbase = bx * 1024; }
    else if (bx == 4) { W = wk; ldw = NKV * HD; cbase = 0; }
    else              { W = wv; ldw = NKV * HD; cbase = 0; }
    const int c = cbase + tid * 4;

    float4 acc[B_];
    #pragma unroll
    for (int r = 0; r < B_; ++r) { acc[r].x = acc[r].y = acc[r].z = acc[r].w = 0.f; }

    const float* wp = W + (size_t)k0 * ldw + c;
    #pragma unroll 8
    for (int kk = 0; kk < KCQ; ++kk) {
        float4 w = *(const float4*)(wp + (size_t)kk * ldw);
        #pragma unroll
        for (int r = 0; r < B_; ++r) {
            float xv = xs[r][kk];
            acc[r].x = fmaf(xv, w.x, acc[r].x);
            acc[r].y = fmaf(xv, w.y, acc[r].y);
            acc[r].z = fmaf(xv, w.z, acc[r].z);
            acc[r].w = fmaf(xv, w.w, acc[r].w);
        }
    }
    const int colg = bx * 1024 + tid * 4;
    #pragma unroll
    for (int r = 0; r < B_; ++r)
        *(float4*)(part + ((size_t)(blockIdx.y * B_ + r)) * QKV_COLS + colg) = acc[r];
}

// ---------------- kernel 2: reduce partials (4-way split) + RoPE ----------------
__global__ __launch_bounds__(256)
void qkv_reduce_rope(const float* __restrict__ part,
                     const float* __restrict__ rot,   // (B, HD, HD)
                     float* __restrict__ qb,
                     float* __restrict__ kb,
                     float* __restrict__ vb) {
    __shared__ float4 red[4][64];
    const int tid = threadIdx.x;
    const int sg  = tid >> 6;                 // split group 0..3
    const int c4l = tid & 63;
    const int col4 = blockIdx.x * 64 + c4l;   // [0, 1536)
    const int r    = blockIdx.y;

    float4 v; v.x = v.y = v.z = v.w = 0.f;
    const int s0 = sg * (KSQ / 4);
    #pragma unroll 8
    for (int s = s0; s < s0 + KSQ / 4; ++s) {
        float4 p = *(const float4*)(part + ((size_t)(s * B_ + r)) * QKV_COLS + col4 * 4);
        v.x += p.x; v.y += p.y; v.z += p.z; v.w += p.w;
    }
    red[sg][c4l] = v;
    __syncthreads();

    if (tid < 64) {
        const int c4 = blockIdx.x * 64 + tid;
        float4 a = red[0][tid], b2 = red[1][tid], c2 = red[2][tid], d2 = red[3][tid];
        float4 vv;
        vv.x = a.x + b2.x + c2.x + d2.x;
        vv.y = a.y + b2.y + c2.y + d2.y;
        vv.z = a.z + b2.z + c2.z + d2.z;
        vv.w = a.w + b2.w + c2.w + d2.w;
        const int col = c4 * 4;
        if (col < DIM + NKV * HD) {
            int hd = col & (HD - 1);
            const float* rm = rot + (size_t)r * HD * HD;
            float c0 = rm[hd * HD + hd];
            float s0r = rm[(hd + 1) * HD + hd];
            float c1 = rm[(hd + 2) * HD + hd + 2];
            float s1r = rm[(hd + 3) * HD + hd + 2];
            float4 o;
            o.x = vv.x * c0 + vv.y * s0r;
            o.y = vv.y * c0 - vv.x * s0r;
            o.z = vv.z * c1 + vv.w * s1r;
            o.w = vv.w * c1 - vv.z * s1r;
            if (col < DIM) *(float4*)(qb + r * DIM + col) = o;
            else           *(float4*)(kb + r * NKV * HD + (col - DIM)) = o;
        } else {
            *(float4*)(vb + r * NKV * HD + (col - DIM - NKV * HD)) = vv;
        }
    }
}

// ---------------- kernel 3: attention, split-L, LDS-staged K ----------------
__global__ __launch_bounds__(256)
void attn_partial(const float* __restrict__ qb,
                  const float* __restrict__ knew,
                  const float* __restrict__ vnew,
                  const float* __restrict__ cache_k,
                  const float* __restrict__ cache_v,
                  const float* __restrict__ mask,     // (NH, B, PAD_LEN)
                  const int* __restrict__ start_pos_p,
                  float* __restrict__ part) {
    const int bg = blockIdx.x;          // 0..63
    const int b  = bg >> 3;
    const int g  = bg & 7;
    const int chunk = blockIdx.y;       // 0..NLCHUNK-1
    const int l0 = chunk * LCHUNK;
    const int tid  = threadIdx.x;
    const int lane = tid & 63;
    const int wave = tid >> 6;
    const int sp = start_pos_p[0];

    __shared__ float k_lds[LCHUNK][HD + 4];   // 64 x 132, float4-aligned
    __shared__ float q_lds[GQ][HD];
    __shared__ float p_lds[GQ][LCHUNK];
    __shared__ float vred[4][GQ][HD];

    // load q: 4 heads x 128 = 128 float4
    if (tid < 128) {
        int qh = tid >> 5;
        int d4 = (tid & 31) * 4;
        *(float4*)&q_lds[qh][d4] = *(const float4*)(qb + b * DIM + (g * GQ + qh) * HD + d4);
    }
    // stage K chunk: 64 rows x 32 float4, coalesced
    const float* kc = cache_k + ((size_t)(b * NKV + g)) * SW * HD;
    const float* knp = knew + (b * NKV + g) * HD;
    #pragma unroll
    for (int i = 0; i < 8; ++i) {
        int idx = i * 256 + tid;          // float4 index
        int r   = idx >> 5;
        int c4  = (idx & 31) * 4;
        int lg  = l0 + r;
        const float* src = (lg == sp) ? knp : (kc + (size_t)lg * HD);
        *(float4*)&k_lds[r][c4] = *(const float4*)(src + c4);
    }
    __syncthreads();

    // QK^T: wave = query head, lane = key row
    const int qh = wave;
    const int row = lane;
    float s = 0.f;
    #pragma unroll 8
    for (int d = 0; d < HD; d += 4) {
        float4 kv = *(const float4*)&k_lds[row][d];
        float4 qv = *(const float4*)&q_lds[qh][d];
        s += kv.x * qv.x + kv.y * qv.y + kv.z * qv.z + kv.w * qv.w;
    }
    const int l = l0 + row;
    float sv = s * SCALE + mask[(((size_t)(g * GQ + qh)) * B_ + b) * PAD_LEN + l];

    // wave softmax (64 rows per head, all in one wave)
    float m = sv;
    #pragma unroll
    for (int off = 32; off > 0; off >>= 1)
        m = fmaxf(m, __shfl_xor(m, off, 64));
    float p = __expf(sv - m);
    float sum = p;
    #pragma unroll
    for (int off = 32; off > 0; off >>= 1)
        sum += __shfl_xor(sum, off, 64);
    p_lds[qh][row] = p;
    __syncthreads();

    // PV: wave owns rows [wave*16, wave*16+16), accumulates all 4 heads
    const int d2 = lane * 2;
    const float* vc  = cache_v + ((size_t)(b * NKV + g)) * SW * HD;
    const float* vnp = vnew + (b * NKV + g) * HD;
    float2 acc[GQ];
    #pragma unroll
    for (int q = 0; q < GQ; ++q) { acc[q].x = 0.f; acc[q].y = 0.f; }
    #pragma unroll 4
    for (int ll = 0; ll < LCHUNK / 4; ++ll) {
        int r  = wave * (LCHUNK / 4) + ll;
        int lg = l0 + r;
        const float* vp = ((lg == sp) ? vnp : (vc + (size_t)lg * HD)) + d2;
        float2 vv = *(const float2*)vp;
        #pragma unroll
        for (int q = 0; q < GQ; ++q) {
            float pp = p_lds[q][r];
            acc[q].x = fmaf(pp, vv.x, acc[q].x);
            acc[q].y = fmaf(pp, vv.y, acc[q].y);
        }
    }
    #pragma unroll
    for (int q = 0; q < GQ; ++q)
        *(float2*)&vred[wave][q][d2] = acc[q];
    __syncthreads();

    // cross-wave reduce + write partial (wave = qh again)
    float2 o; o.x = 0.f; o.y = 0.f;
    #pragma unroll
    for (int w = 0; w < 4; ++w) {
        float2 t = *(const float2*)&vred[w][qh][d2];
        o.x += t.x; o.y += t.y;
    }
    const size_t base = ((size_t)bg * NLCHUNK + chunk) * GQ;
    *(float2*)(part + (base + qh) * (HD + 2) + 2 + d2) = o;
    if (lane == 0) {
        part[(base + qh) * (HD + 2) + 0] = m;
        part[(base + qh) * (HD + 2) + 1] = sum;
    }
}

// ---------------- kernel 4: combine split-L partials ----------------
__global__ __launch_bounds__(128)
void attn_combine(const float* __restrict__ part,
                  float* __restrict__ attnout) {
    const int bg = blockIdx.x;
    const int b  = bg >> 3;
    const int g  = bg & 7;
    const int d  = threadIdx.x;   // 128

    for (int qh = 0; qh < GQ; ++qh) {
        float M = -3.4e38f;
        #pragma unroll 8
        for (int c = 0; c < NLCHUNK; ++c)
            M = fmaxf(M, part[(((size_t)bg * NLCHUNK + c) * GQ + qh) * (HD + 2)]);
        float denom = 0.f, o = 0.f;
        #pragma unroll 8
        for (int c = 0; c < NLCHUNK; ++c) {
            const float* p = part + (((size_t)bg * NLCHUNK + c) * GQ + qh) * (HD + 2);
            float w = __expf(p[0] - M);
            denom += w * p[1];
            o     += w * p[2 + d];
        }
        attnout[b * DIM + (g * GQ + qh) * HD + d] = o / denom;
    }
}

// ---------------- kernel 5: output projection, split-K, float4 cols ----------------
__global__ __launch_bounds__(256)
void oproj_partial(const float* __restrict__ xin,
                   const float* __restrict__ wo,
                   float* __restrict__ part) {
    __shared__ float xs[B_][KCO];            // 8 x 32
    const int tid = threadIdx.x;
    const int k0  = blockIdx.y * KCO;

    if (tid < 64) {
        int r  = tid >> 3;
        int kk = (tid & 7) * 4;
        *(float4*)&xs[r][kk] = *(const float4*)(xin + r * DIM + k0 + kk);
    }
    __syncthreads();

    const int col = blockIdx.x * 1024 + tid * 4;
    float4 acc[B_];
    #pragma unroll
    for (int r = 0; r < B_; ++r) { acc[r].x = acc[r].y = acc[r].z = acc[r].w = 0.f; }

    const float* wp = wo + (size_t)k0 * DIM + col;
    #pragma unroll 8
    for (int kk = 0; kk < KCO; ++kk) {
        float4 w = *(const float4*)(wp + (size_t)kk * DIM);
        #pragma unroll
        for (int r = 0; r < B_; ++r) {
            float xv = xs[r][kk];
            acc[r].x = fmaf(xv, w.x, acc[r].x);
            acc[r].y = fmaf(xv, w.y, acc[r].y);
            acc[r].z = fmaf(xv, w.z, acc[r].z);
            acc[r].w = fmaf(xv, w.w, acc[r].w);
        }
    }
    #pragma unroll
    for (int r = 0; r < B_; ++r)
        *(float4*)(part + ((size_t)(blockIdx.y * B_ + r)) * DIM + col) = acc[r];
}

// ---------------- kernel 6: reduce -> final output ----------------
__global__ __launch_bounds__(256)
void oproj_reduce(const float* __restrict__ part,
                  float* __restrict__ out) {
    __shared__ float4 red[4][64];
    const int tid = threadIdx.x;
    const int sg  = tid >> 6;
    const int c4l = tid & 63;
    const int col4 = blockIdx.x * 64 + c4l;   // [0, 1024)
    const int r    = blockIdx.y;

    float4 v; v.x = v.y = v.z = v.w = 0.f;
    const int s0 = sg * (KSO / 4);
    #pragma unroll 8
    for (int s = s0; s < s0 + KSO / 4; ++s) {
        float4 p = *(const float4*)(part + ((size_t)(s * B_ + r)) * DIM + col4 * 4);
        v.x += p.x; v.y += p.y; v.z += p.z; v.w += p.w;
    }
    red[sg][c4l] = v;
    __syncthreads();

    if (tid < 64) {
        const int c4 = blockIdx.x * 64 + tid;
        float4 a = red[0][tid], b2 = red[1][tid], c2 = red[2][tid], d2 = red[3][tid];
        float4 o;
        o.x = a.x + b2.x + c2.x + d2.x;
        o.y = a.y + b2.y + c2.y + d2.y;
        o.z = a.z + b2.z + c2.z + d2.z;
        o.w = a.w + b2.w + c2.w + d2.w;
        *(float4*)(out + r * DIM + c4 * 4) = o;
    }
}

extern "C" void kernel_launch(void* const* d_in, const int* in_sizes, int n_in,
                              void* d_out, int out_size, void* d_ws, size_t ws_size,
                              hipStream_t stream) {
    const float* x        = (const float*)d_in[0];
    const float* wq       = (const float*)d_in[1];
    const float* wk       = (const float*)d_in[2];
    const float* wv       = (const float*)d_in[3];
    const float* wo       = (const float*)d_in[4];
    const float* rot      = (const float*)d_in[5];
    const float* cache_k  = (const float*)d_in[6];
    const float* cache_v  = (const float*)d_in[7];
    const float* mask     = (const float*)d_in[8];
    const int*   start_pp = (const int*)d_in[9];
    float* ws  = (float*)d_ws;
    float* out = (float*)d_out;

    dim3 gA(6, KSQ);                       // 768 blocks
    qkv_partial<<<gA, 256, 0, stream>>>(x, wq, wk, wv, ws + OFF_QKVP);

    dim3 gB(QKV_COLS / 256, B_);           // (24, 8)
    qkv_reduce_rope<<<gB, 256, 0, stream>>>(ws + OFF_QKVP, rot,
                                            ws + OFF_Q, ws + OFF_K, ws + OFF_V);

    dim3 gC(B_ * NKV, NLCHUNK);            // (64, 32) = 2048 blocks
    attn_partial<<<gC, 256, 0, stream>>>(ws + OFF_Q, ws + OFF_K, ws + OFF_V,
                                         cache_k, cache_v, mask, start_pp,
                                         ws + OFF_AP);

    attn_combine<<<dim3(B_ * NKV), 128, 0, stream>>>(ws + OFF_AP, ws + OFF_AO);

    dim3 gD(4, KSO);                       // 512 blocks
    oproj_partial<<<gD, 256, 0, stream>>>(ws + OFF_AO, wo, ws + OFF_OP);

    dim3 gE(DIM / 256, B_);                // (16, 8)
    oproj_reduce<<<gE, 256, 0, stream>>>(ws + OFF_OP, out);
}